// Round 8
// baseline (185.897 us; speedup 1.0000x reference)
//
#include <hip/hip_runtime.h>

#define NTA 65536
#define NC 1024
#define NO 256
#define HDIM 332
#define HP 352          // H padded to multiple of 32
#define NSP 4
#define NOUT (NTA + NC + NTA*3)   // 263168 f32: en[NTA], E[NC], forces[NTA*3]
#define SORT_CAP (NTA + 256)      // 65792

typedef __attribute__((ext_vector_type(8))) short short8;
typedef __attribute__((ext_vector_type(4))) float f32x4;

// ---- workspace offsets (bytes) ----
#define OFF_CNT   0
#define OFF_CUR   64
#define OFF_START 128        // 8 ints
#define OFF_FLAG  160        // 1 uint: 1 = float inputs are bf16, 0 = f32
#define OFF_SORT  256        // int[65792] -> ends 263424
#define OFF_B1P   263680     // f32[4*352] -> 269312
#define OFF_W2P   269312     // f32[4*352] -> 274944
#define OFF_W1T   274944     // bf16 [4][352][256] -> 995840
#define OFF_W1P   995840     // bf16 [4][256][352] -> 1716736
#define OFF_FACC  1716736    // f32: forces[196608], Eatom[65536], Ecry[1024]

__device__ __forceinline__ unsigned short f2bf(float f){
  unsigned int u = __builtin_bit_cast(unsigned int, f);
  u += 0x7fffu + ((u>>16)&1u);
  return (unsigned short)(u>>16);
}
__device__ __forceinline__ float bf2f(unsigned short h){
  unsigned int u = ((unsigned int)h)<<16;
  return __builtin_bit_cast(float, u);
}
// load a "reference-f32" value that may be stored as bf16 or f32 on device
__device__ __forceinline__ float ldf(const void* p, int idx, int isbf){
  if (isbf) return bf2f(((const unsigned short*)p)[idx]);
  return ((const float*)p)[idx];
}

__global__ void k_init(float* __restrict__ acc, unsigned int* __restrict__ wshead,
                       int* __restrict__ sorted, const unsigned short* __restrict__ posu,
                       unsigned int* __restrict__ flag){
  int i = blockIdx.x*256 + threadIdx.x;   // grid 1028*256 = 263168 exactly
  acc[i] = 0.f;
  if (i < 32) wshead[i] = 0u;
  if (i < SORT_CAP) sorted[i] = -1;
  // dtype probe (kept for robustness; npz evidence says f32 -> flag=0)
  if (blockIdx.x == 1027 && threadIdx.x < 64){
    unsigned short u = posu[2*threadIdx.x];
    int e = (u>>7)&0xFF;
    bool inr = (e >= 110 && e <= 140);
    unsigned long long m = __ballot(inr);
    if (threadIdx.x == 0) flag[0] = (__popcll(m) >= 32) ? 1u : 0u;
  }
}

__global__ void k_count(const int* __restrict__ sym, unsigned int* __restrict__ cnt){
  __shared__ unsigned int h[NSP];
  int t = threadIdx.x;
  if (t < NSP) h[t] = 0u;
  __syncthreads();
  int i = blockIdx.x*256 + t;
  atomicAdd(&h[sym[i]], 1u);
  __syncthreads();
  if (t < NSP) atomicAdd(&cnt[t], h[t]);
}

__global__ void k_starts(const unsigned int* __restrict__ cnt, int* __restrict__ starts){
  if (threadIdx.x == 0){
    int a = 0; starts[0] = 0;
    for (int s=0;s<NSP;s++){ a += (int)(((cnt[s]+63u)>>6)<<6); starts[s+1] = a; }
  }
}

__global__ void k_scatter(const int* __restrict__ sym, const int* __restrict__ starts,
                          unsigned int* __restrict__ cur, int* __restrict__ sorted){
  int i = blockIdx.x*256 + threadIdx.x;
  int s = sym[i];
  int lane = threadIdx.x & 63;
  #pragma unroll
  for (int ss=0; ss<NSP; ss++){
    unsigned long long m = __ballot(s==ss);
    if (s == ss){
      int leader = __builtin_ctzll(m);
      int cw = __popcll(m);
      unsigned int b = 0;
      if (lane == leader) b = atomicAdd(&cur[ss], (unsigned int)cw);
      b = (unsigned int)__shfl((int)b, leader);
      int rank = __popcll(m & ((1ull<<lane) - 1ull));
      sorted[starts[ss] + (int)b + rank] = i;
    }
  }
}

__global__ void k_prepw(const void* __restrict__ W1, const void* __restrict__ b1,
                        const void* __restrict__ W2, const unsigned int* __restrict__ flag,
                        unsigned short* __restrict__ w1t, unsigned short* __restrict__ w1p,
                        float* __restrict__ b1p, float* __restrict__ w2p){
  const int isbf = (int)flag[0];
  int idx = blockIdx.x*256 + threadIdx.x;   // covers 4*352*256 exactly
  int s = idx / (HP*NO);
  int r = idx % (HP*NO);
  int j = r / NO;
  int i = r % NO;
  float v = (j < HDIM) ? ldf(W1, (s*NO + i)*HDIM + j, isbf) : 0.f;
  unsigned short hv = f2bf(v);
  w1t[(s*HP + j)*NO + i] = hv;
  w1p[(s*NO + i)*HP + j] = hv;
  if (i == 0){
    b1p[s*HP + j] = (j < HDIM) ? ldf(b1, s*HDIM + j, isbf) : 0.f;
    w2p[s*HP + j] = (j < HDIM) ? ldf(W2, s*HDIM + j, isbf) : 0.f;
  }
}

// Fused per-tile kernel. Tile = 64 atoms of one species. 4 waves, M-split.
// GEMM1': pre^T[352][64] = W1T[352][256] x feat^T   (K=256, 8 k-steps)
// GEMM2': dfeat^T[256][64] = W1p[256][352] x dpre^T (K=352, 11 k-steps)
// MFMA C/D layout (HW-verified r3 probe): reg q of lane l -> row=(l>>4)*4+q, col=l&15.
__global__ __launch_bounds__(256,2) void k_main(
    const int* __restrict__ sorted, const int* __restrict__ starts,
    const void* __restrict__ pos, const void* __restrict__ Wd,
    const unsigned short* __restrict__ W1T, const unsigned short* __restrict__ W1P,
    const float* __restrict__ b1p, const float* __restrict__ w2p,
    const void* __restrict__ b2g, const unsigned int* __restrict__ flag,
    float* __restrict__ Eatom, float* __restrict__ forces)
{
  extern __shared__ char smem[];
  char* featB = smem;                   // bf16 [64][256], XOR-swizzled rows of 512B
  char* dpB   = smem + 32768;           // bf16 [64] rows x 720B stride
  ushort4* wdT = (ushort4*)(smem + 32768 + 46080);  // [256] {wx,wy,wz,0}

  const int base = blockIdx.x*64;
  if (base >= starts[4]) return;
  const int isbf = (int)flag[0];
  int sp = 0;
  #pragma unroll
  for (int s=1;s<NSP;s++) sp = (base >= starts[s]) ? s : sp;

  const int tid = threadIdx.x;
  const int l = tid & 63;
  const int w = tid >> 6;
  const int c = l & 15;
  const int g = l >> 4;

  {
    float x = ldf(Wd, tid, isbf), y = ldf(Wd, NO+tid, isbf), z = ldf(Wd, 2*NO+tid, isbf);
    ushort4 u; u.x = f2bf(x); u.y = f2bf(y); u.z = f2bf(z); u.w = 0;
    wdT[tid] = u;
  }
  __syncthreads();

  // ---- stage feat tile: thread handles row m=l, 64-col chunk w ----
  {
    const int m = l;
    int a = sorted[base + m];
    float px=0.f, py=0.f, pz=0.f;
    if (a >= 0){ px = ldf(pos,3*a,isbf); py = ldf(pos,3*a+1,isbf); pz = ldf(pos,3*a+2,isbf); }
    const int swz = (m&7)<<4;
    char* rowp = featB + m*512;
    #pragma unroll
    for (int k8=0;k8<8;k8++){
      int i0 = w*64 + k8*8;
      unsigned int pk[4];
      #pragma unroll
      for (int p2=0;p2<4;p2++){
        unsigned short hv[2];
        #pragma unroll
        for (int e2=0;e2<2;e2++){
          ushort4 wv = wdT[i0 + 2*p2 + e2];
          float v = px*bf2f(wv.x) + py*bf2f(wv.y) + pz*bf2f(wv.z);
          float e = __expf(2.f*v);
          hv[e2] = f2bf(1.f - 2.f/(e+1.f));   // tanh
        }
        pk[p2] = (unsigned int)hv[0] | ((unsigned int)hv[1]<<16);
      }
      *(uint4*)(rowp + ((i0*2) ^ swz)) = make_uint4(pk[0],pk[1],pk[2],pk[3]);
    }
  }
  __syncthreads();

  // ---- GEMM1' ----
  const unsigned short* W1Ts = W1T + sp*HP*NO;
  f32x4 acc[6][4];
  #pragma unroll
  for (int t=0;t<6;t++)
    #pragma unroll
    for (int nb=0;nb<4;nb++) acc[t][nb] = f32x4{0.f,0.f,0.f,0.f};
  const int nT1 = (w==3) ? 4 : 6;   // 22 j-frags: 6+6+6+4

  for (int kk=0; kk<8; kk++){
    short8 bfr[4];
    #pragma unroll
    for (int nb=0;nb<4;nb++){
      int m = nb*16 + c;
      bfr[nb] = *(const short8*)(featB + m*512 + ((kk*64 + g*16) ^ ((m&7)<<4)));
    }
    #pragma unroll
    for (int t=0;t<6;t++){
      if (t < nT1){
        const short8 afr = *(const short8*)((const char*)W1Ts + ((6*w+t)*16 + c)*512 + kk*64 + g*16);
        #pragma unroll
        for (int nb=0;nb<4;nb++)
          acc[t][nb] = __builtin_amdgcn_mfma_f32_16x16x32_bf16(afr, bfr[nb], acc[t][nb], 0,0,0);
      }
    }
  }

  // ---- epilogue 1: bias, silu, per-atom energy partials, dpre -> LDS ----
  const float* b1s = b1p + sp*HP;
  const float* w2s = w2p + sp*HP;
  float b2v = (w==0) ? ldf(b2g, sp, isbf) : 0.f;
  float esp[4] = {0.f,0.f,0.f,0.f};
  #pragma unroll
  for (int t=0;t<6;t++){
    if (t < nT1){
      const int j0 = (6*w+t)*16 + g*4;
      const float4 b1v = *(const float4*)(b1s + j0);
      const float4 w2v = *(const float4*)(w2s + j0);
      const float* b1a = (const float*)&b1v;
      const float* w2a = (const float*)&w2v;
      #pragma unroll
      for (int nb=0;nb<4;nb++){
        const int m = nb*16 + c;
        unsigned short dph[4];
        #pragma unroll
        for (int q=0;q<4;q++){
          float pre = acc[t][nb][q] + b1a[q];
          float sg = 1.f/(1.f + __expf(-pre));
          float h = pre*sg;
          esp[nb] += h*w2a[q];
          float dsl = sg*(1.f + pre*(1.f - sg));   // silu'
          dph[q] = f2bf(w2a[q]*dsl);               // dpre
        }
        *(uint2*)(dpB + m*720 + j0*2) =
            make_uint2((unsigned)dph[0] | ((unsigned)dph[1]<<16),
                       (unsigned)dph[2] | ((unsigned)dph[3]<<16));
      }
    }
  }
  #pragma unroll
  for (int nb=0;nb<4;nb++){
    float e = esp[nb];
    e += __shfl_xor(e, 16);
    e += __shfl_xor(e, 32);
    if (g == 0){
      int a = sorted[base + nb*16 + c];
      if (a >= 0) atomicAdd(&Eatom[a], e + b2v);   // 4 wave-partials per atom
    }
  }
  __syncthreads();   // dpB complete

  // ---- GEMM2' ----
  const unsigned short* W1Ps = W1P + sp*NO*HP;
  f32x4 acc2[4][4];
  #pragma unroll
  for (int t2=0;t2<4;t2++)
    #pragma unroll
    for (int nb=0;nb<4;nb++) acc2[t2][nb] = f32x4{0.f,0.f,0.f,0.f};

  for (int kk=0; kk<11; kk++){
    short8 bfr[4];
    #pragma unroll
    for (int nb=0;nb<4;nb++){
      int m = nb*16 + c;
      bfr[nb] = *(const short8*)(dpB + m*720 + kk*64 + g*16);
    }
    #pragma unroll
    for (int t2=0;t2<4;t2++){
      const short8 afr = *(const short8*)((const char*)W1Ps + ((4*w+t2)*16 + c)*704 + kk*64 + g*16);
      #pragma unroll
      for (int nb=0;nb<4;nb++)
        acc2[t2][nb] = __builtin_amdgcn_mfma_f32_16x16x32_bf16(afr, bfr[nb], acc2[t2][nb], 0,0,0);
    }
  }

  // ---- epilogue 2: dpos = (dfeat * (1-feat^2)) @ Wd^T ----
  float fax[4] = {0.f,0.f,0.f,0.f};
  float fay[4] = {0.f,0.f,0.f,0.f};
  float faz[4] = {0.f,0.f,0.f,0.f};
  #pragma unroll
  for (int t2=0;t2<4;t2++){
    const int i0 = (4*w+t2)*16 + g*4;
    #pragma unroll
    for (int nb=0;nb<4;nb++){
      const int m = nb*16 + c;
      uint2 fpk = *(const uint2*)(featB + m*512 + ((i0*2) ^ ((m&7)<<4)));
      unsigned short fh[4];
      fh[0] = (unsigned short)(fpk.x & 0xffffu); fh[1] = (unsigned short)(fpk.x >> 16);
      fh[2] = (unsigned short)(fpk.y & 0xffffu); fh[3] = (unsigned short)(fpk.y >> 16);
      #pragma unroll
      for (int q=0;q<4;q++){
        float ff = bf2f(fh[q]);
        float gsc = acc2[t2][nb][q] * (1.f - ff*ff);
        ushort4 wv = wdT[i0 + q];
        fax[nb] += gsc*bf2f(wv.x);
        fay[nb] += gsc*bf2f(wv.y);
        faz[nb] += gsc*bf2f(wv.z);
      }
    }
  }
  #pragma unroll
  for (int nb=0;nb<4;nb++){
    float x = fax[nb], y = fay[nb], z = faz[nb];
    x += __shfl_xor(x, 16); x += __shfl_xor(x, 32);
    y += __shfl_xor(y, 16); y += __shfl_xor(y, 32);
    z += __shfl_xor(z, 16); z += __shfl_xor(z, 32);
    if (g == 0){
      int a = sorted[base + nb*16 + c];
      if (a >= 0){
        atomicAdd(&forces[3*a+0], x);
        atomicAdd(&forces[3*a+1], y);
        atomicAdd(&forces[3*a+2], z);
      }
    }
  }
}

__global__ void k_seg(const float* __restrict__ Eatom, const int* __restrict__ crys,
                      float* __restrict__ Ecry){
  int i = blockIdx.x*256 + threadIdx.x;   // 256 blocks -> 65536 threads
  atomicAdd(&Ecry[crys[i]], Eatom[i]);
}

// Output: f32, reference order (energies=en[NTA], energy=E[NC], forces[NTA,3])
__global__ void k_out(const float* __restrict__ Eatom, const float* __restrict__ Ecry,
                      const float* __restrict__ Facc, float* __restrict__ out){
  int i = blockIdx.x*256 + threadIdx.x;   // grid covers 263168 exactly
  float v;
  if (i < NTA)            v = Eatom[i];
  else if (i < NTA + NC)  v = Ecry[i - NTA];
  else                    v = Facc[i - NTA - NC];
  out[i] = v;
}

extern "C" void kernel_launch(void* const* d_in, const int* in_sizes, int n_in,
                              void* d_out, int out_size, void* d_ws, size_t ws_size,
                              hipStream_t stream) {
  const int*   symbols    = (const int*)  d_in[0];
  const void*  positions  = d_in[1];
  // d_in[2] cells, d_in[3] pbcs, d_in[4] energyidx: unused by the math
  const int*   crystalidx = (const int*)  d_in[5];
  const void*  Wd         = d_in[6];
  const void*  W1         = d_in[7];
  const void*  b1         = d_in[8];
  const void*  W2         = d_in[9];
  const void*  b2         = d_in[10];
  float* dout = (float*)d_out;   // f32 output buffer (npz-size evidence, r7)

  char* ws = (char*)d_ws;
  unsigned int* cnt    = (unsigned int*)(ws + OFF_CNT);
  unsigned int* cur    = (unsigned int*)(ws + OFF_CUR);
  int*          starts = (int*)         (ws + OFF_START);
  unsigned int* flag   = (unsigned int*)(ws + OFF_FLAG);
  int*          sorted = (int*)         (ws + OFF_SORT);
  float*        b1p    = (float*)       (ws + OFF_B1P);
  float*        w2p    = (float*)       (ws + OFF_W2P);
  unsigned short* w1t  = (unsigned short*)(ws + OFF_W1T);
  unsigned short* w1pp = (unsigned short*)(ws + OFF_W1P);
  float*        Facc   = (float*)       (ws + OFF_FACC);   // forces[196608]
  float*        Eatom  = Facc + NTA*3;                     // [65536]
  float*        Ecry   = Eatom + NTA;                      // [1024]

  hipFuncSetAttribute((const void*)k_main,
                      hipFuncAttributeMaxDynamicSharedMemorySize, 81920);

  k_init   <<<1028,256, 0, stream>>>(Facc, (unsigned int*)ws, sorted,
                                     (const unsigned short*)positions, flag);
  k_count  <<<256, 256, 0, stream>>>(symbols, cnt);
  k_starts <<<1,    64, 0, stream>>>(cnt, starts);
  k_scatter<<<256, 256, 0, stream>>>(symbols, starts, cur, sorted);
  k_prepw  <<<1408,256, 0, stream>>>(W1, b1, W2, flag, w1t, w1pp, b1p, w2p);
  k_main   <<<1028,256, 80896, stream>>>(sorted, starts, positions, Wd,
                                         w1t, w1pp, b1p, w2p, b2, flag,
                                         Eatom, Facc);
  k_seg    <<<256, 256, 0, stream>>>(Eatom, crystalidx, Ecry);
  k_out    <<<1028,256, 0, stream>>>(Eatom, Ecry, Facc, dout);
}